// Round 16
// baseline (132.403 us; speedup 1.0000x reference)
//
#include <hip/hip_runtime.h>

#define N_NODES 100000
#define N_EDGES 1600000
#define D_IN 32
#define D_HID 16
#define D_OUT 2

// dst bucketing: 128 nodes per bucket.
#define NPB 128
#define NB 782                       // ceil(100000/128)
#define NROWS (NB * NPB)             // 100096 padded feature rows
#define CHUNK 6400                   // 250 * 6400 = 1,600,000 exactly
#define BBLOCKS 250
#define EPT 13                       // ceil(6400/512); k=12 valid iff tid<256

// Padded per-bucket record windows (mean fill 2046, 11 sigma headroom).
#define PBC 2560
#define DUMMY_SRC 100000u            // zeroed xr feature row; hr[100000]=0
#define DUMMY_REC ((127u << 17) | DUMMY_SRC)

// LESSONS:
//  (r2-5) LDS f32 atomics: ~270 cyc per wave64 op — bulk tile-scatter via
//         LDS atomics is 174-218 µs, all pipes idle.
//  (r7)   Per-edge global atomic reservation + scattered 4B stores:
//         WRITE_SIZE 23->83 MB, 380 µs. Keep LDS-grouped coalesced
//         write-out + bulk per-(block,bucket) reservation.
//  (r8)   Histogram atomicAdd RETURNS the rank: one atomic pass suffices.
//  (r9)   Post-sort, each dst's records are CONTIGUOUS — per-dst lane
//         teams accumulate with plain stores: zero atomics.
//  (r10)  Ballot-based match-any rank REGRESSED: serial ballot+LDS-RMW
//         chain vs pipelined independent atomics. Keep atomic rank.
//  (r11/12) Grid sizing: <1 block/CU exposes the phase chain, but 2
//         blocks/CU doesn't help either — per-CU LDS-pipe work is
//         partition-invariant. Bin is near its structural floor.
//  (r13)  Cooperative grid.sync fusion REGRESSED 2x: forced co-residency
//         kills block-turnover pipelining. A second launch is cheaper.
//         LDS staging that the same thread writes then reads at the same
//         index is a pure pass-through — keep records in registers.
//  (r14)  Contiguous-run consumers don't need LDS staging at all: read
//         the run directly from global (coalesced within team) — saves
//         the stage pass AND the barrier (more cross-kernel overlap).
//  (r15)  Plateau model: ~12.6M serialized LDS lane-ops / 256 CUs ~ 60 µs
//         + bin phase chain ~45 + launch serialization ~10 = the floor.

__device__ __forceinline__ unsigned bfr(float x) {   // f32 -> bf16 (RNE)
    unsigned u = __float_as_uint(x);
    return (u + 0x7FFFu + ((u >> 16) & 1u)) >> 16;
}
__device__ __forceinline__ float bfu(unsigned lo16) {
    return __uint_as_float(lo16 << 16);
}

// ---------------------------------------------------------------------------
// Fused bin + node-1 transform, single-atomic-pass binning.
// (UNCHANGED from verified round-15 132.2 µs kernel.)
// ---------------------------------------------------------------------------
__global__ __launch_bounds__(512) void k_bin_node1(
    const int* __restrict__ ei, const float* __restrict__ x,
    const float* __restrict__ w_rel, const float* __restrict__ w_root,
    const float* __restrict__ bb,
    unsigned short* __restrict__ xr, float* __restrict__ agg,
    int* __restrict__ gcur, unsigned* __restrict__ recs2)
{
    __shared__ int cnt[NB];
    __shared__ int loff[NB];
    __shared__ int gbase[NB];
    __shared__ unsigned sorted[CHUNK];           // 25.6 KB
    __shared__ unsigned short bkt16[CHUNK];      // 12.8 KB
    __shared__ float s_rel[D_HID * D_IN];
    __shared__ float s_root[D_HID * D_IN];
    __shared__ float s_b[D_HID];
    int blk = blockIdx.x, tid = threadIdx.x;
    int e0 = blk * CHUNK;

    // ---- batch edge loads (independent, ei read once) ----
    int srcs[EPT], dsts[EPT];
#pragma unroll
    for (int k = 0; k < EPT; k++) {
        int off = tid + k * 512;
        bool ok = off < CHUNK;                   // k==12 -> tid<256
        int e = e0 + off;
        srcs[k] = ok ? ei[e] : 0;
        dsts[k] = ok ? ei[N_EDGES + e] : -1;
    }

    for (int i = tid; i < D_HID * D_IN; i += 512) {
        s_rel[i]  = w_rel[i];
        s_root[i] = w_root[i];
    }
    if (tid < D_HID) s_b[tid] = bb[tid];
    for (int i = tid; i < NB; i += 512) cnt[i] = 0;
    __syncthreads();

    // ---- phase A: histogram + rank in ONE atomic pass ----
    int rank[EPT];
#pragma unroll
    for (int k = 0; k < EPT; k++)
        rank[k] = (dsts[k] >= 0) ? atomicAdd(&cnt[dsts[k] >> 7], 1) : 0;

    // ---- phase B: node-1 transform (independent of A) ----
    int node = blk * 512 + tid;                  // 250*512 = 128000 > 100001
    if (node == N_NODES) {                       // dummy zero xr row
        uint4* xp = (uint4*)(xr + (size_t)node * D_HID);
        xp[0] = make_uint4(0, 0, 0, 0);
        xp[1] = make_uint4(0, 0, 0, 0);
    } else if (node < N_NODES) {
        float row[D_IN];
        const float4* xp = (const float4*)(x + (size_t)node * D_IN);
#pragma unroll
        for (int i = 0; i < D_IN / 4; i++) {
            float4 v = xp[i];
            row[4*i+0] = v.x; row[4*i+1] = v.y; row[4*i+2] = v.z; row[4*i+3] = v.w;
        }
        float oa[D_HID], orr[D_HID];
#pragma unroll
        for (int o = 0; o < D_HID; o++) {
            float a = 0.f, r = s_b[o];
#pragma unroll
            for (int k = 0; k < D_IN; k++) {
                a += row[k] * s_rel[o * D_IN + k];
                r += row[k] * s_root[o * D_IN + k];
            }
            oa[o] = a; orr[o] = r;
        }
        unsigned p[8];
#pragma unroll
        for (int i = 0; i < 8; i++)
            p[i] = bfr(oa[2*i]) | (bfr(oa[2*i+1]) << 16);
        uint4* xrp = (uint4*)(xr + (size_t)node * D_HID);
        xrp[0] = make_uint4(p[0], p[1], p[2], p[3]);
        xrp[1] = make_uint4(p[4], p[5], p[6], p[7]);
        float4* aggp = (float4*)(agg + (size_t)node * D_HID);
#pragma unroll
        for (int i = 0; i < D_HID / 4; i++)
            aggp[i] = make_float4(orr[4*i], orr[4*i+1], orr[4*i+2], orr[4*i+3]);
    }
    __syncthreads();

    // ---- phase C: scan (wave 0) || global reservation (waves 1-7) ----
    if (tid < 64) {
        int running = 0;
        for (int c = 0; c < (NB + 63) / 64; c++) {
            int idx = c * 64 + tid;
            int v = (idx < NB) ? cnt[idx] : 0;
            int incl = v;
#pragma unroll
            for (int off = 1; off < 64; off <<= 1) {
                int t = __shfl_up(incl, off);
                if (tid >= off) incl += t;
            }
            if (idx < NB) loff[idx] = running + incl - v;
            running += __shfl(incl, 63);
        }
    } else {
        for (int i = tid - 64; i < NB; i += 448)
            gbase[i] = (cnt[i] > 0) ? atomicAdd(&gcur[i], cnt[i]) : 0;
    }
    __syncthreads();

    // ---- phase D1: placement at loff+rank, NO atomics ----
#pragma unroll
    for (int k = 0; k < EPT; k++) {
        if (dsts[k] >= 0) {
            int bkt = dsts[k] >> 7;
            int p = loff[bkt] + rank[k];
            sorted[p] = ((unsigned)(dsts[k] & (NPB - 1)) << 17) | (unsigned)srcs[k];
            bkt16[p] = (unsigned short)bkt;
        }
    }
    __syncthreads();

    // ---- phase D2: linear write-out (coalesced runs per bucket) ----
    for (int i = tid; i < CHUNK; i += 512) {
        int b = bkt16[i];
        int idx = gbase[b] + (i - loff[b]);
        if (idx < PBC)                             // 11-sigma overflow guard
            recs2[b * PBC + idx] = sorted[i];
    }
}

// ---------------------------------------------------------------------------
// Fused per-bucket sort + layer-1 accumulate + ReLU + layer-2 weight fold.
// Same as verified r15 kernel EXCEPT: sorted write-back vectorized to uint4
// (1 ds_read_b128 + 1 dwordx4 store per 4 records; ~4x fewer LDS ops on the
// contended LDS pipe). Layout/bytes identical for k_acc2.
// ---------------------------------------------------------------------------
__global__ __launch_bounds__(512) void k_sortacc(
    const int* __restrict__ gcur, unsigned* __restrict__ recs2,
    const unsigned short* __restrict__ srcf, const float* __restrict__ agg,
    const float* __restrict__ w_rel2, const float* __restrict__ w_root2,
    const float* __restrict__ bb2,
    float* __restrict__ hr, float* __restrict__ outv,
    unsigned* __restrict__ bbase)
{
    __shared__ __align__(16) unsigned sorted[PBC];
    __shared__ int hist[NPB], base[NPB];
    __shared__ float s_rel2[D_OUT * D_HID];
    __shared__ float s_root2[D_OUT * D_HID];
    __shared__ float s_b2[D_OUT];
    int b = blockIdx.x, tid = threadIdx.x;
    int n = min(gcur[b], PBC);
    unsigned* w = recs2 + (size_t)b * PBC;

    // ---- batch record loads global->reg (no stage[] pass-through) ----
    unsigned rc[PBC / 512];
#pragma unroll
    for (int j = 0; j < PBC / 512; j++) {
        int i = tid + j * 512;
        rc[j] = (i < n) ? w[i] : DUMMY_REC;
    }

    // ---- hoisted: this thread's team row of agg (used only in epilogue) ----
    int t = tid >> 2, l = tid & 3;
    int node = b * NPB + t;
    float acc0 = 0.f, acc1 = 0.f, acc2_ = 0.f, acc3 = 0.f;
    if (node < N_NODES) {
        const float4 r4 = *(const float4*)(agg + (size_t)node * D_HID + l * 4);
        acc0 = r4.x; acc1 = r4.y; acc2_ = r4.z; acc3 = r4.w;
    }

    if (tid < D_OUT * D_HID) {
        s_rel2[tid]  = w_rel2[tid];
        s_root2[tid] = w_root2[tid];
    }
    if (tid < D_OUT) s_b2[tid] = bb2[tid];
    if (tid < NPB) hist[tid] = 0;
    __syncthreads();

    // ---- rank pass: ONE LDS atomic per record ----
    int rk[PBC / 512];
#pragma unroll
    for (int j = 0; j < PBC / 512; j++) {
        int i = tid + j * 512;
        rk[j] = (i < n) ? atomicAdd(&hist[rc[j] >> 17], 1) : -1;
    }
    __syncthreads();

    // ---- wave-0 shuffle scan of 128 bins -> exclusive base ----
    if (tid < 64) {
        int v0 = hist[tid], v1 = hist[tid + 64];
        int s0 = v0, s1 = v1;
#pragma unroll
        for (int off = 1; off < 64; off <<= 1) {
            int t0 = __shfl_up(s0, off);
            int t1 = __shfl_up(s1, off);
            if (tid >= off) { s0 += t0; s1 += t1; }
        }
        int tot0 = __shfl(s0, 63);
        base[tid]      = s0 - v0;
        base[tid + 64] = tot0 + s1 - v1;
    }
    __syncthreads();

    // ---- placement, NO atomics ----
#pragma unroll
    for (int j = 0; j < PBC / 512; j++) {
        if (rk[j] >= 0)
            sorted[base[rc[j] >> 17] + rk[j]] = rc[j];
    }
    __syncthreads();

    // ---- write back sorted, uint4-vectorized (coalesced) for k_acc2 ----
    int n4 = n & ~3;
    for (int i4 = tid * 4; i4 < n4; i4 += 2048) {
        uint4 v4 = *(const uint4*)&sorted[i4];
        *(uint4*)&w[i4] = v4;
    }
    for (int i = n4 + tid; i < n; i += 512) w[i] = sorted[i];
    if (tid < NPB)
        bbase[b * NPB + tid] = (unsigned)base[tid] | ((unsigned)hist[tid] << 16);

    // ---- per-dst team accumulate: 4 lanes/team, zero atomics ----
    int cbase = base[t], c = hist[t];
    for (int r0 = 0; r0 < c; r0 += 8) {
        int m = c - r0;
        uint2 vv[8];
#pragma unroll
        for (int j = 0; j < 8; j++) {
            unsigned src = (j < m) ? (sorted[cbase + r0 + j] & 0x1FFFF) : DUMMY_SRC;
            vv[j] = *(const uint2*)(srcf + (size_t)src * D_HID + l * 4);
        }
#pragma unroll
        for (int j = 0; j < 8; j++) {
            acc0 += bfu(vv[j].x & 0xFFFFu); acc1 += bfu(vv[j].x >> 16);
            acc2_ += bfu(vv[j].y & 0xFFFFu); acc3 += bfu(vv[j].y >> 16);
        }
    }

    // ---- ReLU + layer-2 fold on the in-register row ----
    float h0 = fmaxf(acc0, 0.f), h1 = fmaxf(acc1, 0.f);
    float h2 = fmaxf(acc2_, 0.f), h3 = fmaxf(acc3, 0.f);
    float pr[D_OUT], pp[D_OUT];
#pragma unroll
    for (int o = 0; o < D_OUT; o++) {
        const float* wr = &s_rel2[o * D_HID + l * 4];
        const float* wo = &s_root2[o * D_HID + l * 4];
        pr[o] = h0 * wr[0] + h1 * wr[1] + h2 * wr[2] + h3 * wr[3];
        pp[o] = h0 * wo[0] + h1 * wo[1] + h2 * wo[2] + h3 * wo[3];
    }
#pragma unroll
    for (int m = 1; m < 4; m <<= 1) {
        pr[0] += __shfl_xor(pr[0], m); pr[1] += __shfl_xor(pr[1], m);
        pp[0] += __shfl_xor(pp[0], m); pp[1] += __shfl_xor(pp[1], m);
    }
    if (l == 0) {
        if (node < N_NODES) {
            ((float2*)hr)[node]   = make_float2(pr[0], pr[1]);
            ((float2*)outv)[node] = make_float2(pp[0] + s_b2[0], pp[1] + s_b2[1]);
        } else if (node == N_NODES) {
            ((float2*)hr)[node] = make_float2(0.f, 0.f);   // dummy row
        }
    }
}

// ---------------------------------------------------------------------------
// Layer-2 accumulate: LDS-free, barrier-free. One 4-lane team per dst reads
// its contiguous sorted run directly from global (coalesced), gathers float2
// hr (L2-resident) 4-deep, shfl_xor reduce, plain RMW.
// (UNCHANGED from verified round-15 132.2 µs kernel.)
// ---------------------------------------------------------------------------
__global__ __launch_bounds__(512) void k_acc2(
    const unsigned* __restrict__ recs2, const unsigned* __restrict__ bbase,
    const float* __restrict__ hr, float* __restrict__ outv)
{
    int b = blockIdx.x, tid = threadIdx.x;
    int t = tid >> 2, l = tid & 3;
    unsigned pk = bbase[b * NPB + t];
    int cbase = (int)(pk & 0xFFFFu), c = (int)(pk >> 16);
    int node = b * NPB + t;
    const unsigned* rp = recs2 + (size_t)b * PBC;

    float ax = 0.f, ay = 0.f;
    for (int r0 = 0; r0 < c; r0 += 16) {
        unsigned s4[4];
#pragma unroll
        for (int j = 0; j < 4; j++) {
            int idx = r0 + j * 4 + l;
            s4[j] = (idx < c) ? (rp[cbase + idx] & 0x1FFFF) : DUMMY_SRC;
        }
        float2 v4[4];
#pragma unroll
        for (int j = 0; j < 4; j++) v4[j] = ((const float2*)hr)[s4[j]];
#pragma unroll
        for (int j = 0; j < 4; j++) { ax += v4[j].x; ay += v4[j].y; }
    }
#pragma unroll
    for (int m = 1; m < 4; m <<= 1) {
        ax += __shfl_xor(ax, m); ay += __shfl_xor(ay, m);
    }
    if (l == 0 && node < N_NODES) {
        float2 o = ((const float2*)outv)[node];
        ((float2*)outv)[node] = make_float2(o.x + ax, o.y + ay);
    }
}

extern "C" void kernel_launch(void* const* d_in, const int* in_sizes, int n_in,
                              void* d_out, int out_size, void* d_ws, size_t ws_size,
                              hipStream_t stream) {
    const float* x       = (const float*)d_in[0];
    const int*   ei      = (const int*)  d_in[1];
    const float* w1_rel  = (const float*)d_in[2];
    const float* w1_root = (const float*)d_in[3];
    const float* b1      = (const float*)d_in[4];
    const float* w2_rel  = (const float*)d_in[5];
    const float* w2_root = (const float*)d_in[6];
    const float* b2      = (const float*)d_in[7];
    float* out = (float*)d_out;

    // Workspace (~19 MB; everything rewritten each call):
    float*          agg   = (float*)d_ws;                                   // NROWS*16 f32 (6.4 MB)
    unsigned short* xrh   = (unsigned short*)(agg + (size_t)NROWS * D_HID); // NROWS*16 bf16 (3.2 MB)
    unsigned*       recs2 = (unsigned*)(xrh + (size_t)NROWS * D_HID);       // NB*PBC (8.0 MB)
    float*          hr    = (float*)(recs2 + (size_t)NB * PBC);             // NROWS*2 f32 (0.8 MB)
    unsigned*       bbase = (unsigned*)(hr + (size_t)NROWS * D_OUT);        // NROWS u32 (0.4 MB)
    int*            gcur  = (int*)(bbase + (size_t)NROWS);                  // NB

    hipMemsetAsync(gcur, 0, NB * sizeof(int), stream);

    k_bin_node1<<<dim3(BBLOCKS), dim3(512), 0, stream>>>(
        ei, x, w1_rel, w1_root, b1, xrh, agg, gcur, recs2);

    k_sortacc<<<dim3(NB), dim3(512), 0, stream>>>(
        gcur, recs2, xrh, agg, w2_rel, w2_root, b2, hr, out, bbase);

    k_acc2<<<dim3(NB), dim3(512), 0, stream>>>(recs2, bbase, hr, out);
}